// Round 17
// baseline (79.730 us; speedup 1.0000x reference)
//
#include <hip/hip_runtime.h>
#include <hip/hip_fp16.h>
#include <math.h>

#define KSIZE 31
#define HRAD 15

#define QSCALE (1023.0f / 0.75f)
#define QINV   (0.75f / 1023.0f)
#define QOFF   0.25f

// ws layout in uint4 units: blurq [0, 98304) | bg0q [98304, 196608) |
//                           bg1q [196608, 1769472)
#define OFF_BG0Q 98304
#define OFF_BG1Q 196608

union H8U { float4 f4; __half h[8]; };

// ---------------------------------------------------------------------------
// 10-bit fixed-point RGB pack/unpack (range [-0.25, 0.5])
// ---------------------------------------------------------------------------
__device__ inline unsigned quant3(float r, float g, float b) {
    int qr = (int)((r + QOFF) * QSCALE + 0.5f);
    int qg = (int)((g + QOFF) * QSCALE + 0.5f);
    int qb = (int)((b + QOFF) * QSCALE + 0.5f);
    qr = min(max(qr, 0), 1023);
    qg = min(max(qg, 0), 1023);
    qb = min(max(qb, 0), 1023);
    return (unsigned)(qr | (qg << 10) | (qb << 20));
}

__device__ inline float deqc(unsigned q, int sh) {
    return (float)((q >> sh) & 1023u) * QINV - QOFF;
}

// ---------------------------------------------------------------------------
// Cube-map coordinate math (mirrors reference cube_sample exactly, f32)
// ---------------------------------------------------------------------------
__device__ inline void cube_coords(float x, float y, float z,
                                   int& face, float& u, float& v) {
    float ax = fabsf(x), ay = fabsf(y), az = fabsf(z);
    bool is_x = (ax >= ay) && (ax >= az);
    bool is_y = (!is_x) && (ay >= az);
    float ma, sc, tc;
    if (is_x) {
        if (x >= 0.0f) { face = 0; sc = -z; } else { face = 1; sc = z; }
        ma = ax; tc = -y;
    } else if (is_y) {
        if (y >= 0.0f) { face = 2; tc = z; } else { face = 3; tc = -z; }
        ma = ay; sc = x;
    } else {
        if (z >= 0.0f) { face = 4; sc = x; } else { face = 5; sc = -x; }
        ma = az; tc = -y;
    }
    float inv = 1.0f / fmaxf(ma, 1e-12f);
    u = 0.5f * (sc * inv + 1.0f);
    v = 0.5f * (tc * inv + 1.0f);
}

// corner-record bilinear setup: corners baked; left/top edge -> wx/wy = 0
__device__ inline void nbq_setup(float u, float v, int HW, int face,
                                 int& rec, float& wx, float& wy) {
    float fx = u * (float)HW - 0.5f;
    float fy = v * (float)HW - 0.5f;
    float x0 = floorf(fx), y0 = floorf(fy);
    wx = fx - x0;
    wy = fy - y0;
    int xi = (int)x0, yi = (int)y0;
    if (xi < 0) { xi = 0; wx = 0.0f; }
    if (yi < 0) { yi = 0; wy = 0.0f; }
    rec = (face * HW + yi) * HW + xi;
}

// ---------------------------------------------------------------------------
// Inline f32 Gaussian weights (tid%128 -> lvl=(tid>>5)&3, tap=tid&31)
// ---------------------------------------------------------------------------
__device__ inline void weights_inline(int tid, float wS[4][32]) {
    const float ss[4] = {8.f, 4.f, 2.f, 1.f};
    int lvl = (tid >> 5) & 3;
    int tap = tid & 31;
    float d = (float)tap - 15.0f;
    float q = d / ss[lvl];
    float g = (tap < KSIZE) ? expf(-0.5f * q * q) : 0.0f;
    float s = g;
#pragma unroll
    for (int k = 16; k; k >>= 1) s += __shfl_xor(s, k, 32);
    if (tid < 128) wS[lvl][tap] = g / s;
}

// ---------------------------------------------------------------------------
// k1 (fused by block range, 768 blocks) — r16-proven, byte-identical:
//   blocks [0, 384)   : bg1q pack, 8-row tile + 1 halo row staged in LDS
//   blocks [384, 768) : horizontal 4-level blur (2 rows/block) + bg0q emit
// ---------------------------------------------------------------------------
__global__ __launch_bounds__(256)
void prep1(const float* __restrict__ bg0, const float* __restrict__ bg1,
           float4* __restrict__ tmpH, uint4* __restrict__ bg0q,
           uint4* __restrict__ bg1q) {
    __shared__ float4 sm4[3456];       // 13,824 B
    float* sm = (float*)sm4;
    int b = blockIdx.x;
    int tid = threadIdx.x;

    if (b < 384) {
        int face  = b / 64;
        int ytile = (b % 64) * 8;
        for (int i = tid; i < 9 * 384; i += 256) {
            int r  = i / 384;
            int c4 = i - r * 384;
            int gy = min(ytile + r, 511);
            sm4[r * 384 + c4] =
                ((const float4*)(bg1 + (size_t)(face * 512 + gy) * 1536))[c4];
        }
        __syncthreads();
#pragma unroll
        for (int i = 0; i < 16; ++i) {
            int idx = i * 256 + tid;
            int yl  = idx >> 9;
            int x   = idx & 511;
            int x1  = min(x + 1, 511);
            const float* rA = sm + (size_t)yl * 1536;
            const float* rB = sm + (size_t)(yl + 1) * 1536;
            uint4 r;
            r.x = quant3(rA[x * 3 + 0],  rA[x * 3 + 1],  rA[x * 3 + 2]);
            r.y = quant3(rA[x1 * 3 + 0], rA[x1 * 3 + 1], rA[x1 * 3 + 2]);
            r.z = quant3(rB[x * 3 + 0],  rB[x * 3 + 1],  rB[x * 3 + 2]);
            r.w = quant3(rB[x1 * 3 + 0], rB[x1 * 3 + 1], rB[x1 * 3 + 2]);
            bg1q[(size_t)(face * 512 + ytile + yl) * 512 + x] = r;
        }
        return;
    }

    float (*rows)[2][384] = (float (*)[2][384])sm;
    float (*wS)[32] = (float (*)[32])(sm + 1536);

    int bid  = b - 384;
    int unit = tid >> 7;
    int lane = tid & 127;
    int face = bid / 64;
    int yrow = (bid % 64) * 2 + unit;

    weights_inline(tid, wS);

    int ynext = min(yrow + 1, 127);
    const float* srcA = bg0 + (size_t)(face * 128 + yrow) * 384;
    const float* srcB = bg0 + (size_t)(face * 128 + ynext) * 384;
    for (int k = lane; k < 384; k += 128) {
        rows[unit][0][k] = srcA[k];
        rows[unit][1][k] = srcB[k];
    }
    __syncthreads();

    int x = lane;
    float a[4][3] = {};
    for (int t = 0; t < KSIZE; ++t) {
        int xx = x + t - HRAD;
        if (xx >= 0 && xx < 128) {
            float r0 = rows[unit][0][xx * 3 + 0];
            float r1 = rows[unit][0][xx * 3 + 1];
            float r2 = rows[unit][0][xx * 3 + 2];
#pragma unroll
            for (int l = 0; l < 4; ++l) {
                float w = wS[l][t];
                a[l][0] += w * r0; a[l][1] += w * r1; a[l][2] += w * r2;
            }
        }
    }
    size_t idx = (size_t)(face * 128 + yrow) * 128 + x;
    H8U ta, tb;
#pragma unroll
    for (int l = 0; l < 2; ++l) {
        ta.h[l * 4 + 0] = __float2half(a[l][0]);
        ta.h[l * 4 + 1] = __float2half(a[l][1]);
        ta.h[l * 4 + 2] = __float2half(a[l][2]);
        ta.h[l * 4 + 3] = __float2half(0.0f);
        tb.h[l * 4 + 0] = __float2half(a[2 + l][0]);
        tb.h[l * 4 + 1] = __float2half(a[2 + l][1]);
        tb.h[l * 4 + 2] = __float2half(a[2 + l][2]);
        tb.h[l * 4 + 3] = __float2half(0.0f);
    }
    tmpH[idx * 2 + 0] = ta.f4;
    tmpH[idx * 2 + 1] = tb.f4;

    int x1 = min(x + 1, 127);
    uint4 r;
    r.x = quant3(rows[unit][0][x * 3 + 0], rows[unit][0][x * 3 + 1], rows[unit][0][x * 3 + 2]);
    r.y = quant3(rows[unit][0][x1 * 3 + 0], rows[unit][0][x1 * 3 + 1], rows[unit][0][x1 * 3 + 2]);
    r.z = quant3(rows[unit][1][x * 3 + 0], rows[unit][1][x * 3 + 1], rows[unit][1][x * 3 + 2]);
    r.w = quant3(rows[unit][1][x1 * 3 + 0], rows[unit][1][x1 * 3 + 1], rows[unit][1][x1 * 3 + 2]);
    bg0q[idx] = r;
}

// ---------------------------------------------------------------------------
// k2: vertical blur (768 blocks; 2 levels per thread) — r16-proven.
// ---------------------------------------------------------------------------
__global__ __launch_bounds__(256)
void vblur(const float4* __restrict__ tmpH, uint2* __restrict__ blurq2) {
    __shared__ float wS[4][32];
    int b    = blockIdx.x;
    int tid  = threadIdx.x;
    int yrow = b & 127;
    int face = b >> 7;

    weights_inline(tid, wS);
    __syncthreads();

    int x    = tid >> 1;
    int half = tid & 1;
    float a0 = 0.f, a1 = 0.f, a2 = 0.f, a3 = 0.f, a4 = 0.f, a5 = 0.f;
    int ylo = max(yrow - HRAD, 0);
    int yhi = min(yrow + HRAD, 127);
    for (int yy = ylo; yy <= yhi; ++yy) {
        int t = yy - yrow + HRAD;
        H8U q;
        q.f4 = tmpH[((size_t)(face * 128 + yy) * 128 + x) * 2 + half];
        float wA = wS[half * 2 + 0][t];
        float wB = wS[half * 2 + 1][t];
        a0 += wA * __half2float(q.h[0]);
        a1 += wA * __half2float(q.h[1]);
        a2 += wA * __half2float(q.h[2]);
        a3 += wB * __half2float(q.h[4]);
        a4 += wB * __half2float(q.h[5]);
        a5 += wB * __half2float(q.h[6]);
    }
    uint2 o;
    o.x = quant3(a0, a1, a2);
    o.y = quant3(a3, a4, a5);
    blurq2[((size_t)(face * 128 + yrow) * 128 + x) * 2 + half] = o;
}

// ---------------------------------------------------------------------------
// Shade: 4 rays per thread. Branchless unified LOAD phase (4 indices per ray
// into the contiguous ws texture array), then divergent blend. Per-path
// arithmetic byte-identical to r12.
// ---------------------------------------------------------------------------
__global__ __launch_bounds__(256)
void shade4(const float4* __restrict__ vd4, const float4* __restrict__ sa4,
            const uint4* __restrict__ ws, float4* __restrict__ out4,
            int nquads) {
    int q = blockIdx.x * blockDim.x + threadIdx.x;
    if (q >= nquads) return;

    float4 a = vd4[3 * q + 0];
    float4 b = vd4[3 * q + 1];
    float4 c = vd4[3 * q + 2];
    float4 s = sa4[q];

    float X[4] = {a.x, a.w, b.z, c.y};
    float Y[4] = {a.y, b.x, b.w, c.z};
    float Z[4] = {a.z, b.y, c.x, c.w};
    float S[4] = {s.x, s.y, s.z, s.w};

    const float saTexel = (float)(4.0 * M_PI / (6.0 * 512.0 * 512.0));

    int   I[4][4];
    float P[4][7];
    bool  MK[4];

    // ---- setup phase (VALU only, predication-friendly) ----
#pragma unroll
    for (int r = 0; r < 4; ++r) {
        int face; float u, v;
        cube_coords(X[r], Y[r], Z[r], face, u, v);

        float m = logf(S[r] / saTexel);
        m = m / 1.3862943611198906f;   // f32(log(4))
        m = m * 0.5f;
        m = fminf(fmaxf(m, 0.0f), 3.0f);
        bool masked = (m >= 2.0f);
        MK[r] = masked;

        if (masked) {
            float fx = u * 128.0f - 0.5f;
            float fy = v * 128.0f - 0.5f;
            float xf = floorf(fx), yf = floorf(fy);
            float wx = fx - xf, wy = fy - yf;
            int x0i = min(max((int)xf, 0), 127);
            int x1i = min(max((int)xf + 1, 0), 127);
            int y0i = min(max((int)yf, 0), 127);
            int y1i = min(max((int)yf + 1, 0), 127);
            int base = face << 14;
            I[r][0] = base + y0i * 128 + x0i;
            I[r][1] = base + y0i * 128 + x1i;
            I[r][2] = base + y1i * 128 + x0i;
            I[r][3] = base + y1i * 128 + x1i;

            float w0 = 1.0f - fminf(fabsf(3.0f - m), 1.0f);
            float w1 = 1.0f - fminf(fabsf(2.5f - m), 1.0f);
            float w2 = 1.0f - fminf(fabsf(2.0f - m), 1.0f);
            float w3 = 1.0f - fminf(fabsf(1.5f - m), 1.0f);
            float inv = 1.0f / fmaxf(w0 + w1 + w2 + w3, 1e-8f);
            P[r][0] = wx; P[r][1] = wy;
            P[r][2] = w0; P[r][3] = w1; P[r][4] = w2; P[r][5] = w3;
            P[r][6] = inv;
        } else {
            int r0; float wx0, wy0;
            nbq_setup(u, v, 128, face, r0, wx0, wy0);
            int r1; float wx1, wy1;
            nbq_setup(u, v, 512, face, r1, wx1, wy1);
            I[r][0] = OFF_BG0Q + r0;
            I[r][1] = OFF_BG1Q + r1;
            I[r][2] = OFF_BG0Q + r0;   // pad (same line)
            I[r][3] = OFF_BG1Q + r1;   // pad (same line)
            P[r][0] = wx0; P[r][1] = wy0;
            P[r][2] = wx1; P[r][3] = wy1;
            P[r][4] = 0.f; P[r][5] = 0.f; P[r][6] = 0.f;
        }
    }

    // ---- unified load phase: 16 back-to-back gathers ----
    uint4 Q[4][4];
#pragma unroll
    for (int r = 0; r < 4; ++r) {
#pragma unroll
        for (int k = 0; k < 4; ++k) {
            Q[r][k] = ws[I[r][k]];
        }
    }

    // ---- blend phase (divergent, VALU only) ----
    float R[12];
#pragma unroll
    for (int r = 0; r < 4; ++r) {
        if (MK[r]) {
            float wx = P[r][0], wy = P[r][1];
            float w0 = P[r][2], w1 = P[r][3], w2 = P[r][4], w3 = P[r][5];
            float inv = P[r][6];
            uint4 q00 = Q[r][0], q10 = Q[r][1], q01 = Q[r][2], q11 = Q[r][3];
#pragma unroll
            for (int ch = 0; ch < 3; ++ch) {
                int sh = ch * 10;
                float v00 = w0 * deqc(q00.x, sh) + w1 * deqc(q00.y, sh) +
                            w2 * deqc(q00.z, sh) + w3 * deqc(q00.w, sh);
                float v10 = w0 * deqc(q10.x, sh) + w1 * deqc(q10.y, sh) +
                            w2 * deqc(q10.z, sh) + w3 * deqc(q10.w, sh);
                float v01 = w0 * deqc(q01.x, sh) + w1 * deqc(q01.y, sh) +
                            w2 * deqc(q01.z, sh) + w3 * deqc(q01.w, sh);
                float v11 = w0 * deqc(q11.x, sh) + w1 * deqc(q11.y, sh) +
                            w2 * deqc(q11.z, sh) + w3 * deqc(q11.w, sh);
                float top = v00 * (1.0f - wx) + v10 * wx;
                float bot = v01 * (1.0f - wx) + v11 * wx;
                R[3 * r + ch] = (top * (1.0f - wy) + bot * wy) * inv;
            }
        } else {
            float wx0 = P[r][0], wy0 = P[r][1];
            float wx1 = P[r][2], wy1 = P[r][3];
            uint4 p0 = Q[r][0], p1 = Q[r][1];
#pragma unroll
            for (int ch = 0; ch < 3; ++ch) {
                int sh = ch * 10;
                float t0 = deqc(p0.x, sh) * (1.0f - wx0) + deqc(p0.y, sh) * wx0;
                float b0 = deqc(p0.z, sh) * (1.0f - wx0) + deqc(p0.w, sh) * wx0;
                float c0 = t0 * (1.0f - wy0) + b0 * wy0;
                float t1 = deqc(p1.x, sh) * (1.0f - wx1) + deqc(p1.y, sh) * wx1;
                float b1 = deqc(p1.z, sh) * (1.0f - wx1) + deqc(p1.w, sh) * wx1;
                float c1 = t1 * (1.0f - wy1) + b1 * wy1;
                R[3 * r + ch] = c0 + 0.5f * c1;
            }
        }
    }

    out4[3 * q + 0] = make_float4(R[0], R[1], R[2],  R[3]);
    out4[3 * q + 1] = make_float4(R[4], R[5], R[6],  R[7]);
    out4[3 * q + 2] = make_float4(R[8], R[9], R[10], R[11]);
}

// ---------------------------------------------------------------------------
extern "C" void kernel_launch(void* const* d_in, const int* in_sizes, int n_in,
                              void* d_out, int out_size, void* d_ws, size_t ws_size,
                              hipStream_t stream) {
    const float* viewdirs = (const float*)d_in[0];   // (B,3)
    const float* saSample = (const float*)d_in[1];   // (B,1)
    const float* bg0      = (const float*)d_in[2];   // (6,128,128,3)
    const float* bg1      = (const float*)d_in[3];   // (6,512,512,3)
    float* out = (float*)d_out;

    int B = in_sizes[0] / 3;          // 2097152
    int nquads = B / 4;

    // ws layout (31.2 MB): blurq | bg0q | bg1q contiguous (uint4), then tmpH
    uint4*  wsq   = (uint4*)d_ws;
    uint4*  blurq = wsq;
    uint4*  bg0q  = wsq + OFF_BG0Q;
    uint4*  bg1q  = wsq + OFF_BG1Q;
    float4* tmpH  = (float4*)(bg1q + 1572864);

    prep1<<<768, 256, 0, stream>>>(bg0, bg1, tmpH, bg0q, bg1q);
    vblur<<<768, 256, 0, stream>>>(tmpH, (uint2*)blurq);

    int blocks = (nquads + 255) / 256;
    shade4<<<blocks, 256, 0, stream>>>((const float4*)viewdirs,
                                       (const float4*)saSample,
                                       wsq, (float4*)out, nquads);
}

// Round 18
// 78.212 us; speedup vs baseline: 1.0194x; 1.0194x over previous
//
#include <hip/hip_runtime.h>
#include <hip/hip_fp16.h>
#include <math.h>

#define KSIZE 31
#define HRAD 15

#define QSCALE (1023.0f / 0.75f)
#define QINV   (0.75f / 1023.0f)
#define QOFF   0.25f

union H8U { float4 f4; __half h[8]; };

// ---------------------------------------------------------------------------
// 10-bit fixed-point RGB pack/unpack (range [-0.25, 0.5])
// ---------------------------------------------------------------------------
__device__ inline unsigned quant3(float r, float g, float b) {
    int qr = (int)((r + QOFF) * QSCALE + 0.5f);
    int qg = (int)((g + QOFF) * QSCALE + 0.5f);
    int qb = (int)((b + QOFF) * QSCALE + 0.5f);
    qr = min(max(qr, 0), 1023);
    qg = min(max(qg, 0), 1023);
    qb = min(max(qb, 0), 1023);
    return (unsigned)(qr | (qg << 10) | (qb << 20));
}

__device__ inline float deqc(unsigned q, int sh) {
    return (float)((q >> sh) & 1023u) * QINV - QOFF;
}

// ---------------------------------------------------------------------------
// Cube-map coordinate math (mirrors reference cube_sample exactly, f32)
// ---------------------------------------------------------------------------
__device__ inline void cube_coords(float x, float y, float z,
                                   int& face, float& u, float& v) {
    float ax = fabsf(x), ay = fabsf(y), az = fabsf(z);
    bool is_x = (ax >= ay) && (ax >= az);
    bool is_y = (!is_x) && (ay >= az);
    float ma, sc, tc;
    if (is_x) {
        if (x >= 0.0f) { face = 0; sc = -z; } else { face = 1; sc = z; }
        ma = ax; tc = -y;
    } else if (is_y) {
        if (y >= 0.0f) { face = 2; tc = z; } else { face = 3; tc = -z; }
        ma = ay; sc = x;
    } else {
        if (z >= 0.0f) { face = 4; sc = x; } else { face = 5; sc = -x; }
        ma = az; tc = -y;
    }
    float inv = 1.0f / fmaxf(ma, 1e-12f);
    u = 0.5f * (sc * inv + 1.0f);
    v = 0.5f * (tc * inv + 1.0f);
}

// corner-record bilinear setup: corners baked; left/top edge -> wx/wy = 0
__device__ inline void nbq_setup(float u, float v, int HW, int face,
                                 int& rec, float& wx, float& wy) {
    float fx = u * (float)HW - 0.5f;
    float fy = v * (float)HW - 0.5f;
    float x0 = floorf(fx), y0 = floorf(fy);
    wx = fx - x0;
    wy = fy - y0;
    int xi = (int)x0, yi = (int)y0;
    if (xi < 0) { xi = 0; wx = 0.0f; }
    if (yi < 0) { yi = 0; wy = 0.0f; }
    rec = (face * HW + yi) * HW + xi;
}

// ---------------------------------------------------------------------------
// Inline f32 Gaussian weights (tid%128 -> lvl=(tid>>5)&3, tap=tid&31)
// ---------------------------------------------------------------------------
__device__ inline void weights_inline(int tid, float wS[4][32]) {
    const float ss[4] = {8.f, 4.f, 2.f, 1.f};
    int lvl = (tid >> 5) & 3;
    int tap = tid & 31;
    float d = (float)tap - 15.0f;
    float q = d / ss[lvl];
    float g = (tap < KSIZE) ? expf(-0.5f * q * q) : 0.0f;
    float s = g;
#pragma unroll
    for (int k = 16; k; k >>= 1) s += __shfl_xor(s, k, 32);
    if (tid < 128) wS[lvl][tap] = g / s;
}

// ---------------------------------------------------------------------------
// k1 (fused by block range, 768 blocks):
//   blocks [0, 384)   : bg1q pack, 8-row tile + 1 halo row staged in LDS
//   blocks [384, 768) : horizontal 4-level blur (2 rows/block) + bg0q emit
// ---------------------------------------------------------------------------
__global__ __launch_bounds__(256)
void prep1(const float* __restrict__ bg0, const float* __restrict__ bg1,
           float4* __restrict__ tmpH, uint4* __restrict__ bg0q,
           uint4* __restrict__ bg1q) {
    __shared__ float4 sm4[3456];       // 13,824 B
    float* sm = (float*)sm4;
    int b = blockIdx.x;
    int tid = threadIdx.x;

    if (b < 384) {
        // ---- bg1 pack: face = b/64, rows [ytile, ytile+8) ----
        int face  = b / 64;
        int ytile = (b % 64) * 8;
        for (int i = tid; i < 9 * 384; i += 256) {   // 384 float4 per row
            int r  = i / 384;
            int c4 = i - r * 384;
            int gy = min(ytile + r, 511);
            sm4[r * 384 + c4] =
                ((const float4*)(bg1 + (size_t)(face * 512 + gy) * 1536))[c4];
        }
        __syncthreads();
#pragma unroll
        for (int i = 0; i < 16; ++i) {
            int idx = i * 256 + tid;        // 0..4095
            int yl  = idx >> 9;             // 0..7
            int x   = idx & 511;
            int x1  = min(x + 1, 511);
            const float* rA = sm + (size_t)yl * 1536;
            const float* rB = sm + (size_t)(yl + 1) * 1536;
            uint4 r;
            r.x = quant3(rA[x * 3 + 0],  rA[x * 3 + 1],  rA[x * 3 + 2]);
            r.y = quant3(rA[x1 * 3 + 0], rA[x1 * 3 + 1], rA[x1 * 3 + 2]);
            r.z = quant3(rB[x * 3 + 0],  rB[x * 3 + 1],  rB[x * 3 + 2]);
            r.w = quant3(rB[x1 * 3 + 0], rB[x1 * 3 + 1], rB[x1 * 3 + 2]);
            bg1q[(size_t)(face * 512 + ytile + yl) * 512 + x] = r;
        }
        return;
    }

    // ---- hblur branch ----
    float (*rows)[2][384] = (float (*)[2][384])sm;
    float (*wS)[32] = (float (*)[32])(sm + 1536);

    int bid  = b - 384;                // 0..383
    int unit = tid >> 7;               // 0 or 1
    int lane = tid & 127;
    int face = bid / 64;
    int yrow = (bid % 64) * 2 + unit;

    weights_inline(tid, wS);

    int ynext = min(yrow + 1, 127);
    const float* srcA = bg0 + (size_t)(face * 128 + yrow) * 384;
    const float* srcB = bg0 + (size_t)(face * 128 + ynext) * 384;
    for (int k = lane; k < 384; k += 128) {
        rows[unit][0][k] = srcA[k];
        rows[unit][1][k] = srcB[k];
    }
    __syncthreads();

    int x = lane;
    float a[4][3] = {};
    for (int t = 0; t < KSIZE; ++t) {
        int xx = x + t - HRAD;
        if (xx >= 0 && xx < 128) {
            float r0 = rows[unit][0][xx * 3 + 0];
            float r1 = rows[unit][0][xx * 3 + 1];
            float r2 = rows[unit][0][xx * 3 + 2];
#pragma unroll
            for (int l = 0; l < 4; ++l) {
                float w = wS[l][t];
                a[l][0] += w * r0; a[l][1] += w * r1; a[l][2] += w * r2;
            }
        }
    }
    size_t idx = (size_t)(face * 128 + yrow) * 128 + x;
    H8U ta, tb;
#pragma unroll
    for (int l = 0; l < 2; ++l) {
        ta.h[l * 4 + 0] = __float2half(a[l][0]);
        ta.h[l * 4 + 1] = __float2half(a[l][1]);
        ta.h[l * 4 + 2] = __float2half(a[l][2]);
        ta.h[l * 4 + 3] = __float2half(0.0f);
        tb.h[l * 4 + 0] = __float2half(a[2 + l][0]);
        tb.h[l * 4 + 1] = __float2half(a[2 + l][1]);
        tb.h[l * 4 + 2] = __float2half(a[2 + l][2]);
        tb.h[l * 4 + 3] = __float2half(0.0f);
    }
    tmpH[idx * 2 + 0] = ta.f4;
    tmpH[idx * 2 + 1] = tb.f4;

    // bg0 corner record for (x, yrow)
    int x1 = min(x + 1, 127);
    uint4 r;
    r.x = quant3(rows[unit][0][x * 3 + 0], rows[unit][0][x * 3 + 1], rows[unit][0][x * 3 + 2]);
    r.y = quant3(rows[unit][0][x1 * 3 + 0], rows[unit][0][x1 * 3 + 1], rows[unit][0][x1 * 3 + 2]);
    r.z = quant3(rows[unit][1][x * 3 + 0], rows[unit][1][x * 3 + 1], rows[unit][1][x * 3 + 2]);
    r.w = quant3(rows[unit][1][x1 * 3 + 0], rows[unit][1][x1 * 3 + 1], rows[unit][1][x1 * 3 + 2]);
    bg0q[idx] = r;
}

// ---------------------------------------------------------------------------
// k2: vertical blur (768 blocks, one row each; 2 levels per thread)
// ---------------------------------------------------------------------------
__global__ __launch_bounds__(256)
void vblur(const float4* __restrict__ tmpH, uint2* __restrict__ blurq2) {
    __shared__ float wS[4][32];
    int b    = blockIdx.x;             // 0..767
    int tid  = threadIdx.x;
    int yrow = b & 127;
    int face = b >> 7;

    weights_inline(tid, wS);
    __syncthreads();

    int x    = tid >> 1;
    int half = tid & 1;                // 0: levels 0,1   1: levels 2,3
    float a0 = 0.f, a1 = 0.f, a2 = 0.f, a3 = 0.f, a4 = 0.f, a5 = 0.f;
    int ylo = max(yrow - HRAD, 0);
    int yhi = min(yrow + HRAD, 127);
    for (int yy = ylo; yy <= yhi; ++yy) {
        int t = yy - yrow + HRAD;
        H8U q;
        q.f4 = tmpH[((size_t)(face * 128 + yy) * 128 + x) * 2 + half];
        float wA = wS[half * 2 + 0][t];
        float wB = wS[half * 2 + 1][t];
        a0 += wA * __half2float(q.h[0]);
        a1 += wA * __half2float(q.h[1]);
        a2 += wA * __half2float(q.h[2]);
        a3 += wB * __half2float(q.h[4]);
        a4 += wB * __half2float(q.h[5]);
        a5 += wB * __half2float(q.h[6]);
    }
    uint2 o;
    o.x = quant3(a0, a1, a2);
    o.y = quant3(a3, a4, a5);
    blurq2[((size_t)(face * 128 + yrow) * 128 + x) * 2 + half] = o;
}

// ---------------------------------------------------------------------------
// Per-ray shading (r12-proven, byte-identical)
// ---------------------------------------------------------------------------
__device__ inline void shade_one(float x, float y, float z, float sa,
                                 const uint4* __restrict__ bg0q,
                                 const uint4* __restrict__ bg1q,
                                 const uint4* __restrict__ blurq,
                                 float* __restrict__ R) {
    int face; float u, v;
    cube_coords(x, y, z, face, u, v);

    const float saTexel = (float)(4.0 * M_PI / (6.0 * 512.0 * 512.0));
    float m = logf(sa / saTexel);
    m = m / 1.3862943611198906f;   // f32(log(4))
    m = m * 0.5f;
    m = fminf(fmaxf(m, 0.0f), 3.0f);

    if (m >= 2.0f) {
        float fx = u * 128.0f - 0.5f;
        float fy = v * 128.0f - 0.5f;
        float xf = floorf(fx), yf = floorf(fy);
        float wx = fx - xf, wy = fy - yf;
        int x0i = min(max((int)xf, 0), 127);
        int x1i = min(max((int)xf + 1, 0), 127);
        int y0i = min(max((int)yf, 0), 127);
        int y1i = min(max((int)yf + 1, 0), 127);
        int base = face << 14;
        uint4 q00 = blurq[base + y0i * 128 + x0i];
        uint4 q10 = blurq[base + y0i * 128 + x1i];
        uint4 q01 = blurq[base + y1i * 128 + x0i];
        uint4 q11 = blurq[base + y1i * 128 + x1i];

        float w0 = 1.0f - fminf(fabsf(3.0f - m), 1.0f);
        float w1 = 1.0f - fminf(fabsf(2.5f - m), 1.0f);
        float w2 = 1.0f - fminf(fabsf(2.0f - m), 1.0f);
        float w3 = 1.0f - fminf(fabsf(1.5f - m), 1.0f);
        float inv = 1.0f / fmaxf(w0 + w1 + w2 + w3, 1e-8f);

#pragma unroll
        for (int c = 0; c < 3; ++c) {
            int sh = c * 10;
            float v00 = w0 * deqc(q00.x, sh) + w1 * deqc(q00.y, sh) +
                        w2 * deqc(q00.z, sh) + w3 * deqc(q00.w, sh);
            float v10 = w0 * deqc(q10.x, sh) + w1 * deqc(q10.y, sh) +
                        w2 * deqc(q10.z, sh) + w3 * deqc(q10.w, sh);
            float v01 = w0 * deqc(q01.x, sh) + w1 * deqc(q01.y, sh) +
                        w2 * deqc(q01.z, sh) + w3 * deqc(q01.w, sh);
            float v11 = w0 * deqc(q11.x, sh) + w1 * deqc(q11.y, sh) +
                        w2 * deqc(q11.z, sh) + w3 * deqc(q11.w, sh);
            float top = v00 * (1.0f - wx) + v10 * wx;
            float bot = v01 * (1.0f - wx) + v11 * wx;
            R[c] = (top * (1.0f - wy) + bot * wy) * inv;
        }
    } else {
        int r0; float wx0, wy0;
        nbq_setup(u, v, 128, face, r0, wx0, wy0);
        int r1; float wx1, wy1;
        nbq_setup(u, v, 512, face, r1, wx1, wy1);
        uint4 p0 = bg0q[r0];
        uint4 p1 = bg1q[r1];
#pragma unroll
        for (int c = 0; c < 3; ++c) {
            int sh = c * 10;
            float t0 = deqc(p0.x, sh) * (1.0f - wx0) + deqc(p0.y, sh) * wx0;
            float b0 = deqc(p0.z, sh) * (1.0f - wx0) + deqc(p0.w, sh) * wx0;
            float c0 = t0 * (1.0f - wy0) + b0 * wy0;
            float t1 = deqc(p1.x, sh) * (1.0f - wx1) + deqc(p1.y, sh) * wx1;
            float b1 = deqc(p1.z, sh) * (1.0f - wx1) + deqc(p1.w, sh) * wx1;
            float c1 = t1 * (1.0f - wy1) + b1 * wy1;
            R[c] = c0 + 0.5f * c1;
        }
    }
}

// ---------------------------------------------------------------------------
// Shade: 4 rays per thread, vectorized stream I/O.
// ---------------------------------------------------------------------------
__global__ __launch_bounds__(256)
void shade4(const float4* __restrict__ vd4, const float4* __restrict__ sa4,
            const uint4* __restrict__ bg0q, const uint4* __restrict__ bg1q,
            const uint4* __restrict__ blurq, float4* __restrict__ out4,
            int nquads) {
    int q = blockIdx.x * blockDim.x + threadIdx.x;
    if (q >= nquads) return;

    float4 a = vd4[3 * q + 0];
    float4 b = vd4[3 * q + 1];
    float4 c = vd4[3 * q + 2];
    float4 s = sa4[q];

    float X[4] = {a.x, a.w, b.z, c.y};
    float Y[4] = {a.y, b.x, b.w, c.z};
    float Z[4] = {a.z, b.y, c.x, c.w};
    float S[4] = {s.x, s.y, s.z, s.w};

    float R[12];
#pragma unroll
    for (int r = 0; r < 4; ++r) {
        shade_one(X[r], Y[r], Z[r], S[r], bg0q, bg1q, blurq, &R[3 * r]);
    }

    out4[3 * q + 0] = make_float4(R[0], R[1], R[2],  R[3]);
    out4[3 * q + 1] = make_float4(R[4], R[5], R[6],  R[7]);
    out4[3 * q + 2] = make_float4(R[8], R[9], R[10], R[11]);
}

// ---------------------------------------------------------------------------
extern "C" void kernel_launch(void* const* d_in, const int* in_sizes, int n_in,
                              void* d_out, int out_size, void* d_ws, size_t ws_size,
                              hipStream_t stream) {
    const float* viewdirs = (const float*)d_in[0];   // (B,3)
    const float* saSample = (const float*)d_in[1];   // (B,1)
    const float* bg0      = (const float*)d_in[2];   // (6,128,128,3)
    const float* bg1      = (const float*)d_in[3];   // (6,512,512,3)
    float* out = (float*)d_out;

    int B = in_sizes[0] / 3;          // 2097152
    int nquads = B / 4;

    // ws layout (31.2 MB):
    //   blurq : 98,304 uint4    (1.5 MB)
    //   bg0q  : 98,304 uint4    (1.5 MB)
    //   bg1q  : 1,572,864 uint4 (25.2 MB)
    //   tmpH  : 196,608 float4  (3.0 MB)
    uint4*  blurq = (uint4*)d_ws;
    uint4*  bg0q  = blurq + 98304;
    uint4*  bg1q  = bg0q + 98304;
    float4* tmpH  = (float4*)(bg1q + 1572864);

    prep1<<<768, 256, 0, stream>>>(bg0, bg1, tmpH, bg0q, bg1q);
    vblur<<<768, 256, 0, stream>>>(tmpH, (uint2*)blurq);

    int blocks = (nquads + 255) / 256;
    shade4<<<blocks, 256, 0, stream>>>((const float4*)viewdirs,
                                       (const float4*)saSample,
                                       bg0q, bg1q, blurq,
                                       (float4*)out, nquads);
}